// Round 7
// baseline (223.816 us; speedup 1.0000x reference)
//
#include <hip/hip_runtime.h>
#include <hip/hip_cooperative_groups.h>
#include <stdint.h>

#define BATCH 512
#define D_IN 1024
#define D_OUT 1024
#define BITSZ 128
#define N_STEPS (D_IN - 2)  // 1022

// Table covers idx in [IBASE, 1024). P(any idx < IBASE) ~ 65536 * 2^-64 ~ 4e-15;
// a direct-cipher fallback in phase C keeps exactness for the impossible case.
#define IBASE 960
#define ICAP 64  // table rows per t column

// ws layout (nothing needs zeroing)
#define WS_V_OFF 0u
#define WS_V_BYTES (BATCH * BITSZ * 4u)            // v[b*128+t]  (3-kernel fallback)
#define WS_VT_OFF (WS_V_OFF + WS_V_BYTES)
#define WS_VT_BYTES (BITSZ * BATCH * 4u)           // vT[t*512+b]
#define WS_TAB_OFF (WS_VT_OFF + WS_VT_BYTES)
#define WS_TAB_BYTES (BITSZ * ICAP * 32u * 4u)     // 1 MB
#define WS_NEEDED (WS_TAB_OFF + WS_TAB_BYTES)

// phase-C transposed staging: 32 d-word columns, padded stride (132*4B = 528B:
// 16B-aligned columns; bank(jj,wrd) = (4*wrd+jj)%32 -> spread on writes).
#define TSTRIDE 132

struct TFKeys { uint32_t xk0, xk1, wk0, wk1, ck0, ck1; };

__host__ __device__ __forceinline__ uint32_t rotl32(uint32_t x, uint32_t d) {
  return (x << d) | (x >> (32u - d));
}

// Threefry-2x32, 20 rounds, exactly as jax/_src/prng.py lowering.
__host__ __device__ __forceinline__ void threefry2x32(uint32_t k0, uint32_t k1,
                                                      uint32_t& x0, uint32_t& x1) {
  const uint32_t k2 = k0 ^ k1 ^ 0x1BD11BDAu;
  x0 += k0; x1 += k1;
#define TFR(r) { x0 += x1; x1 = rotl32(x1, (r)); x1 ^= x0; }
  TFR(13) TFR(15) TFR(26) TFR(6)
  x0 += k1; x1 += k2 + 1u;
  TFR(17) TFR(29) TFR(16) TFR(24)
  x0 += k2; x1 += k0 + 2u;
  TFR(13) TFR(15) TFR(26) TFR(6)
  x0 += k0; x1 += k1 + 3u;
  TFR(17) TFR(29) TFR(16) TFR(24)
  x0 += k1; x1 += k2 + 4u;
  TFR(13) TFR(15) TFR(26) TFR(6)
  x0 += k2; x1 += k0 + 5u;
#undef TFR
}

// jax_threefry_partitionable random_bits -> uniform [0,1):
// counts=(0,n), 20-round threefry, 32-bit fold, mantissa trick.
__device__ __forceinline__ float runif(uint32_t k0, uint32_t k1, uint32_t n) {
  uint32_t x0 = 0u, x1 = n;
  threefry2x32(k0, k1, x0, x1);
  const uint32_t b = x0 ^ x1;
  return __uint_as_float((b >> 9) | 0x3f800000u) - 1.0f;
}

// idx = max row s+1 whose coin is False, scanned top-down in speculative
// ILP-4 batches (4 independent ciphers hide the dependent threefry chain).
__device__ __forceinline__ int scan_idx(uint32_t bt, uint32_t ck0, uint32_t ck1) {
  int idx = 0;
  int s;
  for (s = N_STEPS - 1; s >= 3; s -= 4) {
    const float u0 = runif(ck0, ck1, ((uint32_t)(s)     << 16) + bt);
    const float u1 = runif(ck0, ck1, ((uint32_t)(s - 1) << 16) + bt);
    const float u2 = runif(ck0, ck1, ((uint32_t)(s - 2) << 16) + bt);
    const float u3 = runif(ck0, ck1, ((uint32_t)(s - 3) << 16) + bt);
    if (u0 > 0.5f) { idx = s + 1; break; }
    if (u1 > 0.5f) { idx = s;     break; }
    if (u2 > 0.5f) { idx = s - 1; break; }
    if (u3 > 0.5f) { idx = s - 2; break; }
  }
  if (idx == 0 && s < 3) {  // tail: s = 1 and s = 0
    const float u0 = runif(ck0, ck1, (1u << 16) + bt);
    const float u1 = runif(ck0, ck1, bt);
    if (u0 > 0.5f)      idx = 2;
    else if (u1 > 0.5f) idx = 1;
  }
  return idx;
}

// ---------------- Fused cooperative kernel: 512 blocks x 512 threads ----------
// Blocks 0..127 (== t): scan all b, write vT, build presence, emit table rows.
// grid.sync()
// All blocks (== b): accumulate from table (r6 k_acc body).
__global__ void __launch_bounds__(512) k_fused(const float* __restrict__ x,
                                               const float* __restrict__ w,
                                               int* __restrict__ vt,
                                               uint32_t* __restrict__ tab,
                                               float* __restrict__ out,
                                               TFKeys K) {
  const int g = blockIdx.x;
  const int tid = threadIdx.x;

  __shared__ uint32_t s_bm[2];
  __shared__ int s_rows[ICAP];
  __shared__ __align__(16) uint32_t s_tab2[32 * TSTRIDE];  // 16.9 KB
  __shared__ int s_list[BITSZ];
  __shared__ int s_wcnt[2];
  __shared__ int s_anyfb;

  if (g < BITSZ) {
    const int t = g;
    if (tid < 2) s_bm[tid] = 0u;
    __syncthreads();

    // ---- phase A: one scan per thread (b = tid) ----
    const int b = tid;
    const int idx = scan_idx(((uint32_t)b << 7) + (uint32_t)t, K.ck0, K.ck1);
    // x_bits linear index: b*(D_IN*BITSZ) + idx*BITSZ + t
    const float ux = runif(K.xk0, K.xk1,
        ((uint32_t)b << 17) + ((uint32_t)idx << 7) + (uint32_t)t);
    const int xb = (ux <= x[b * D_IN + idx]) ? 1 : 0;
    vt[t * BATCH + b] = xb ? idx : -1;  // coalesced per block
    if (xb && idx >= IBASE) {
      const int bp = idx - IBASE;
      atomicOr(&s_bm[bp >> 5], 1u << (bp & 31));
    }
    __syncthreads();

    // ---- phase B: emit table rows for present idx ----
    const unsigned long long bm = (unsigned long long)s_bm[0] |
                                  ((unsigned long long)s_bm[1] << 32);
    const int cnt = __popcll(bm);
    if (tid < 64 && ((bm >> tid) & 1ull))
      s_rows[__popcll(bm & ((1ull << tid) - 1ull))] = tid;
    __syncthreads();

    const int d0 = tid, d1 = tid + 512;
    const int lane = tid & 63;
    const int wb0 = (d0 >> 5) & ~1;  // even word pair for this wave, low half
    const int wb1 = (d1 >> 5) & ~1;  // high half
    for (int r = 0; r < cnt; ++r) {
      const int j = s_rows[r];
      const int i = IBASE + j;
      const float wa = w[i * D_OUT + d0];
      const float wbv = w[i * D_OUT + d1];
      // w_bits linear index: i*(D_OUT*BITSZ) + d*BITSZ + t
      const float u0 = runif(K.wk0, K.wk1,
          ((uint32_t)i << 17) + ((uint32_t)d0 << 7) + (uint32_t)t);
      const float u1 = runif(K.wk0, K.wk1,
          ((uint32_t)i << 17) + ((uint32_t)d1 << 7) + (uint32_t)t);
      const unsigned long long m0 = __ballot(u0 <= wa);
      const unsigned long long m1 = __ballot(u1 <= wbv);
      uint32_t* row = tab + (((t << 6) + j) << 5);
      if (lane == 0)  { row[wb0]     = (uint32_t)m0;
                        row[wb1]     = (uint32_t)m1; }
      if (lane == 32) { row[wb0 + 1] = (uint32_t)(m0 >> 32);
                        row[wb1 + 1] = (uint32_t)(m1 >> 32); }
    }
  }

  __threadfence();  // make vt/tab visible device-wide (cross-XCD)
  cooperative_groups::this_grid().sync();
  __threadfence();

  // ---- phase C: block == b, accumulate ----
  const int b = g;
  if (tid == 0) s_anyfb = 0;

  unsigned long long mb = 0;
  int code = -1;
  bool act = false;
  if (tid < BITSZ) {
    code = vt[tid * BATCH + b];  // t = tid
    act = code >= 0;
    mb = __ballot(act);
    if ((tid & 63) == 0) s_wcnt[tid >> 6] = __popcll(mb);
  }
  __syncthreads();
  const int m = s_wcnt[0] + s_wcnt[1];
  const int m4 = (m + 3) & ~3;
  if (tid < BITSZ && act) {
    const int lane = tid & 63;
    const int pos = ((tid >= 64) ? s_wcnt[0] : 0) +
                    __popcll(mb & ((1ull << lane) - 1ull));
    s_list[pos] = (code << 7) | tid;  // idx<<7 | t
    if (code < IBASE) atomicOr(&s_anyfb, 1);
  }
  __syncthreads();

  if (s_anyfb == 0) {
    const int wrd = tid & 31;
    for (int jj = tid >> 5; jj < m; jj += 16) {
      const int e = s_list[jj];
      const int i = e >> 7, t = e & 127;
      s_tab2[wrd * TSTRIDE + jj] = tab[(((t << 6) + (i - IBASE)) << 5) + wrd];
    }
    if (tid < 32)
      for (int jj = m; jj < m4; ++jj) s_tab2[tid * TSTRIDE + jj] = 0u;
    __syncthreads();

    const int dw0 = tid >> 5, db = tid & 31;
    const uint32_t* c0 = &s_tab2[dw0 * TSTRIDE];
    const uint32_t* c1 = &s_tab2[(dw0 + 16) * TSTRIDE];
    int a0 = 0, a1 = 0;
    for (int k = 0; k < m4; k += 4) {
      const uint4 r0 = *(const uint4*)(c0 + k);  // ds_read_b128, broadcast
      const uint4 r1 = *(const uint4*)(c1 + k);
      a0 += (r0.x >> db) & 1u; a0 += (r0.y >> db) & 1u;
      a0 += (r0.z >> db) & 1u; a0 += (r0.w >> db) & 1u;
      a1 += (r1.x >> db) & 1u; a1 += (r1.y >> db) & 1u;
      a1 += (r1.z >> db) & 1u; a1 += (r1.w >> db) & 1u;
    }
    out[b * D_OUT + tid]       = (float)a0 * (1.0f / (float)BITSZ);
    out[b * D_OUT + tid + 512] = (float)a1 * (1.0f / (float)BITSZ);
  } else {
    // exactness fallback (idx < IBASE): direct ciphers for both d's
    const int d0 = tid, d1 = tid + 512;
    int a0 = 0, a1 = 0;
    for (int jj = 0; jj < m; ++jj) {
      const int e = s_list[jj];
      const int i = e >> 7, t = e & 127;
      const float u0 = runif(K.wk0, K.wk1,
          ((uint32_t)i << 17) + ((uint32_t)d0 << 7) + (uint32_t)t);
      const float u1 = runif(K.wk0, K.wk1,
          ((uint32_t)i << 17) + ((uint32_t)d1 << 7) + (uint32_t)t);
      a0 += (u0 <= w[i * D_OUT + d0]) ? 1 : 0;
      a1 += (u1 <= w[i * D_OUT + d1]) ? 1 : 0;
    }
    out[b * D_OUT + d0] = (float)a0 * (1.0f / (float)BITSZ);
    out[b * D_OUT + d1] = (float)a1 * (1.0f / (float)BITSZ);
  }
}

// ---------------- 3-kernel fallback path (r6, proven) ----------------
__global__ void __launch_bounds__(256) k_idx(const float* __restrict__ x,
                                             int* __restrict__ v,
                                             int* __restrict__ vt,
                                             uint32_t ck0, uint32_t ck1,
                                             uint32_t xk0, uint32_t xk1,
                                             int use_tab) {
  const int tid = blockIdx.x * 256 + threadIdx.x;
  const int b = tid >> 7;
  const int t = tid & 127;
  const int idx = scan_idx((uint32_t)tid, ck0, ck1);
  const float ux = runif(xk0, xk1,
      ((uint32_t)b << 17) + ((uint32_t)idx << 7) + (uint32_t)t);
  const int xb = (ux <= x[b * D_IN + idx]) ? 1 : 0;
  const int val = xb ? idx : -1;
  v[tid] = val;
  if (use_tab) vt[t * BATCH + b] = val;
}

__global__ void __launch_bounds__(1024) k_tab(const float* __restrict__ w,
                                              const int* __restrict__ vt,
                                              uint32_t* __restrict__ tab,
                                              uint32_t wk0, uint32_t wk1) {
  const int t = blockIdx.x >> 1;
  const int h = blockIdx.x & 1;
  const int tid = threadIdx.x;

  __shared__ uint32_t s_bm[2];
  __shared__ int s_rows[ICAP];
  if (tid < 2) s_bm[tid] = 0u;
  __syncthreads();

  unsigned long long m64 = 0;
  if (tid < BATCH) {
    const int code = vt[t * BATCH + tid];
    if (code >= IBASE) m64 = 1ull << (code - IBASE);
  }
  for (int off = 32; off; off >>= 1) m64 |= __shfl_down(m64, off);
  if ((tid & 63) == 0 && tid < BATCH) {
    if ((uint32_t)m64)         atomicOr(&s_bm[0], (uint32_t)m64);
    if ((uint32_t)(m64 >> 32)) atomicOr(&s_bm[1], (uint32_t)(m64 >> 32));
  }
  __syncthreads();

  const unsigned long long bm = (unsigned long long)s_bm[0] |
                                ((unsigned long long)s_bm[1] << 32);
  const int cnt = __popcll(bm);
  if (tid < 64 && ((bm >> tid) & 1ull))
    s_rows[__popcll(bm & ((1ull << tid) - 1ull))] = tid;
  __syncthreads();

  const int gph = (tid < 512) ? 0 : 1;
  const int dl = (tid < 512) ? tid : (tid - 512);
  const int d = h * 512 + dl;
  const int lane = tid & 63;
  const int wbase = (d >> 5) & ~1;
  const float* wcol = w + d;
  for (int r = gph; r < cnt; r += 2) {
    const int j = s_rows[r];
    const int i = IBASE + j;
    const float u = runif(wk0, wk1,
        ((uint32_t)i << 17) + ((uint32_t)d << 7) + (uint32_t)t);
    const unsigned long long mbv = __ballot(u <= wcol[i * D_OUT]);
    uint32_t* row = tab + (((t << 6) + j) << 5);
    if (lane == 0)  row[wbase]     = (uint32_t)mbv;
    if (lane == 32) row[wbase + 1] = (uint32_t)(mbv >> 32);
  }
}

__global__ void __launch_bounds__(512) k_acc(const float* __restrict__ w,
                                             const int* __restrict__ v,
                                             const uint32_t* __restrict__ tab,
                                             float* __restrict__ out,
                                             uint32_t wk0, uint32_t wk1,
                                             int use_tab) {
  const int b = blockIdx.x;
  const int tid = threadIdx.x;

  __shared__ __align__(16) uint32_t s_tab2[32 * TSTRIDE];
  __shared__ int s_list[BITSZ];
  __shared__ int s_wcnt[2];
  __shared__ int s_anyfb;

  if (tid == 0) s_anyfb = use_tab ? 0 : 1;

  unsigned long long mb = 0;
  int code = -1;
  bool act = false;
  if (tid < BITSZ) {
    code = v[b * BITSZ + tid];
    act = code >= 0;
    mb = __ballot(act);
    if ((tid & 63) == 0) s_wcnt[tid >> 6] = __popcll(mb);
  }
  __syncthreads();
  const int m = s_wcnt[0] + s_wcnt[1];
  const int m4 = (m + 3) & ~3;
  if (tid < BITSZ && act) {
    const int lane = tid & 63;
    const int pos = ((tid >= 64) ? s_wcnt[0] : 0) +
                    __popcll(mb & ((1ull << lane) - 1ull));
    s_list[pos] = (code << 7) | tid;
    if (code < IBASE) atomicOr(&s_anyfb, 1);
  }
  __syncthreads();

  if (s_anyfb == 0) {
    const int wrd = tid & 31;
    for (int jj = tid >> 5; jj < m; jj += 16) {
      const int e = s_list[jj];
      const int i = e >> 7, t = e & 127;
      s_tab2[wrd * TSTRIDE + jj] = tab[(((t << 6) + (i - IBASE)) << 5) + wrd];
    }
    if (tid < 32)
      for (int jj = m; jj < m4; ++jj) s_tab2[tid * TSTRIDE + jj] = 0u;
    __syncthreads();

    const int dw0 = tid >> 5, db = tid & 31;
    const uint32_t* c0 = &s_tab2[dw0 * TSTRIDE];
    const uint32_t* c1 = &s_tab2[(dw0 + 16) * TSTRIDE];
    int a0 = 0, a1 = 0;
    for (int k = 0; k < m4; k += 4) {
      const uint4 r0 = *(const uint4*)(c0 + k);
      const uint4 r1 = *(const uint4*)(c1 + k);
      a0 += (r0.x >> db) & 1u; a0 += (r0.y >> db) & 1u;
      a0 += (r0.z >> db) & 1u; a0 += (r0.w >> db) & 1u;
      a1 += (r1.x >> db) & 1u; a1 += (r1.y >> db) & 1u;
      a1 += (r1.z >> db) & 1u; a1 += (r1.w >> db) & 1u;
    }
    out[b * D_OUT + tid]       = (float)a0 * (1.0f / (float)BITSZ);
    out[b * D_OUT + tid + 512] = (float)a1 * (1.0f / (float)BITSZ);
  } else {
    const int d0 = tid, d1 = tid + 512;
    int a0 = 0, a1 = 0;
    for (int jj = 0; jj < m; ++jj) {
      const int e = s_list[jj];
      const int i = e >> 7, t = e & 127;
      const float u0 = runif(wk0, wk1,
          ((uint32_t)i << 17) + ((uint32_t)d0 << 7) + (uint32_t)t);
      const float u1 = runif(wk0, wk1,
          ((uint32_t)i << 17) + ((uint32_t)d1 << 7) + (uint32_t)t);
      a0 += (u0 <= w[i * D_OUT + d0]) ? 1 : 0;
      a1 += (u1 <= w[i * D_OUT + d1]) ? 1 : 0;
    }
    out[b * D_OUT + d0] = (float)a0 * (1.0f / (float)BITSZ);
    out[b * D_OUT + d1] = (float)a1 * (1.0f / (float)BITSZ);
  }
}

static TFKeys derive_keys() {
  TFKeys K;
  // partitionable split: key_i = both output words of E_{(0,42)}(0, i)
  uint32_t a0 = 0, a1 = 0; threefry2x32(0u, 42u, a0, a1); K.xk0 = a0; K.xk1 = a1;
  uint32_t b0 = 0, b1 = 1; threefry2x32(0u, 42u, b0, b1); K.wk0 = b0; K.wk1 = b1;
  uint32_t c0 = 0, c1 = 2; threefry2x32(0u, 42u, c0, c1); K.ck0 = c0; K.ck1 = c1;
  return K;
}

extern "C" void kernel_launch(void* const* d_in, const int* in_sizes, int n_in,
                              void* d_out, int out_size, void* d_ws, size_t ws_size,
                              hipStream_t stream) {
  const float* x = (const float*)d_in[0];
  const float* w = (const float*)d_in[1];
  if (n_in >= 2 && in_sizes[0] == D_IN * D_OUT && in_sizes[1] == BATCH * D_IN) {
    const float* tmp = x; x = w; w = tmp;
  }
  float* out = (float*)d_out;
  char* ws = (char*)d_ws;
  int* v = (int*)(ws + WS_V_OFF);
  int* vt = (int*)(ws + WS_VT_OFF);
  uint32_t* tab = (uint32_t*)(ws + WS_TAB_OFF);

  const int use_tab = (ws_size >= WS_NEEDED) ? 1 : 0;
  const TFKeys K = derive_keys();

  // Try the single-node cooperative path (deterministic: same check every call).
  bool coop = false;
  if (use_tab) {
    int perCU = 0, nCU = 0;
    if (hipOccupancyMaxActiveBlocksPerMultiprocessor(&perCU, (const void*)k_fused,
                                                     512, 0) == hipSuccess &&
        hipDeviceGetAttribute(&nCU, hipDeviceAttributeMultiprocessorCount, 0) ==
            hipSuccess &&
        (long)perCU * nCU >= BATCH) {
      void* args[] = {(void*)&x, (void*)&w, (void*)&vt, (void*)&tab,
                      (void*)&out, (void*)&K};
      if (hipLaunchCooperativeKernel((const void*)k_fused, dim3(BATCH),
                                     dim3(512), args, 0, stream) == hipSuccess)
        coop = true;
    }
  }
  if (coop) return;

  // Fallback: proven 3-kernel path (bit-identical output).
  hipLaunchKernelGGL(k_idx, dim3((BATCH * BITSZ) / 256), dim3(256), 0, stream,
                     x, v, vt, K.ck0, K.ck1, K.xk0, K.xk1, use_tab);
  if (use_tab)
    hipLaunchKernelGGL(k_tab, dim3(BITSZ * 2), dim3(1024), 0, stream,
                       w, vt, tab, K.wk0, K.wk1);
  hipLaunchKernelGGL(k_acc, dim3(BATCH), dim3(512), 0, stream,
                     w, v, tab, out, K.wk0, K.wk1, use_tab);
}

// Round 8
// 199.759 us; speedup vs baseline: 1.1204x; 1.1204x over previous
//
#include <hip/hip_runtime.h>
#include <stdint.h>

#define BATCH 512
#define D_IN 1024
#define D_OUT 1024
#define BITSZ 128
#define N_STEPS (D_IN - 2)  // 1022

// Table covers idx in [IBASE, 1024). P(any idx < IBASE) ~ 65536 * 2^-64 ~ 4e-15;
// a direct-cipher fallback in phase C keeps exactness for the impossible case.
#define IBASE 960
#define ICAP 64  // table rows per t column

#define NBLK 512
#define NTHR 512

// ws layout (nothing needs zeroing; barrier self-inits via magic word)
#define WS_V_OFF 0u
#define WS_V_BYTES (BATCH * BITSZ * 4u)            // v[b*128+t]   (fallback path)
#define WS_VT_OFF (WS_V_OFF + WS_V_BYTES)
#define WS_VT_BYTES (BITSZ * BATCH * 4u)           // vT[t*512+b]
#define WS_TAB_OFF (WS_VT_OFF + WS_VT_BYTES)
#define WS_TAB_BYTES (BITSZ * ICAP * 32u * 4u)     // 1 MB
#define WS_BAR_OFF (WS_TAB_OFF + WS_TAB_BYTES)
#define WS_BAR_BYTES 1024u                          // magic/sense/master + cnt[8]
#define WS_NEEDED (WS_BAR_OFF + WS_BAR_BYTES)

// phase-C transposed staging: 32 d-word columns, padded stride (132*4B = 528B:
// 16B-aligned columns; bank(jj,wrd) = (4*wrd+jj)%32 -> spread on writes).
#define TSTRIDE 132

#define BAR_MAGIC 0x5EEDBA44u

struct TFKeys { uint32_t xk0, xk1, wk0, wk1, ck0, ck1; };

__host__ __device__ __forceinline__ uint32_t rotl32(uint32_t x, uint32_t d) {
  return (x << d) | (x >> (32u - d));
}

// Threefry-2x32, 20 rounds, exactly as jax/_src/prng.py lowering.
__host__ __device__ __forceinline__ void threefry2x32(uint32_t k0, uint32_t k1,
                                                      uint32_t& x0, uint32_t& x1) {
  const uint32_t k2 = k0 ^ k1 ^ 0x1BD11BDAu;
  x0 += k0; x1 += k1;
#define TFR(r) { x0 += x1; x1 = rotl32(x1, (r)); x1 ^= x0; }
  TFR(13) TFR(15) TFR(26) TFR(6)
  x0 += k1; x1 += k2 + 1u;
  TFR(17) TFR(29) TFR(16) TFR(24)
  x0 += k2; x1 += k0 + 2u;
  TFR(13) TFR(15) TFR(26) TFR(6)
  x0 += k0; x1 += k1 + 3u;
  TFR(17) TFR(29) TFR(16) TFR(24)
  x0 += k1; x1 += k2 + 4u;
  TFR(13) TFR(15) TFR(26) TFR(6)
  x0 += k2; x1 += k0 + 5u;
#undef TFR
}

// jax_threefry_partitionable random_bits -> uniform [0,1):
// counts=(0,n), 20-round threefry, 32-bit fold, mantissa trick.
__device__ __forceinline__ float runif(uint32_t k0, uint32_t k1, uint32_t n) {
  uint32_t x0 = 0u, x1 = n;
  threefry2x32(k0, k1, x0, x1);
  const uint32_t b = x0 ^ x1;
  return __uint_as_float((b >> 9) | 0x3f800000u) - 1.0f;
}

// idx = max row s+1 whose coin is False, scanned top-down in speculative
// ILP-4 batches (4 independent ciphers hide the dependent threefry chain).
__device__ __forceinline__ int scan_idx(uint32_t bt, uint32_t ck0, uint32_t ck1) {
  int idx = 0;
  int s;
  for (s = N_STEPS - 1; s >= 3; s -= 4) {
    const float u0 = runif(ck0, ck1, ((uint32_t)(s)     << 16) + bt);
    const float u1 = runif(ck0, ck1, ((uint32_t)(s - 1) << 16) + bt);
    const float u2 = runif(ck0, ck1, ((uint32_t)(s - 2) << 16) + bt);
    const float u3 = runif(ck0, ck1, ((uint32_t)(s - 3) << 16) + bt);
    if (u0 > 0.5f) { idx = s + 1; break; }
    if (u1 > 0.5f) { idx = s;     break; }
    if (u2 > 0.5f) { idx = s - 1; break; }
    if (u3 > 0.5f) { idx = s - 2; break; }
  }
  if (idx == 0 && s < 3) {  // tail: s = 1 and s = 0
    const float u0 = runif(ck0, ck1, (1u << 16) + bt);
    const float u1 = runif(ck0, ck1, bt);
    if (u0 > 0.5f)      idx = 2;
    else if (u1 > 0.5f) idx = 1;
  }
  return idx;
}

// Sense-reversing grid barrier with 8-way tree counters and magic-word
// self-init (survives the one-time 0xAA ws poison; calls are serialized so
// inter-call state is quiescent: cnt==0, sense uniform).
__device__ __forceinline__ void grid_barrier(uint32_t* bar) {
  __threadfence();   // release this thread's global writes
  __syncthreads();   // whole block done writing
  if (threadIdx.x == 0) {
    uint32_t* magic  = bar + 0;
    uint32_t* sense  = bar + 1;
    uint32_t* master = bar + 2;
    uint32_t* cnt    = bar + 16;  // cnt[g] at bar[16 + g*16] (64B apart)
    if (blockIdx.x == 0) {
      if (__hip_atomic_load(magic, __ATOMIC_ACQUIRE, __HIP_MEMORY_SCOPE_AGENT)
          != BAR_MAGIC) {
        __hip_atomic_store(sense, 0u, __ATOMIC_RELAXED, __HIP_MEMORY_SCOPE_AGENT);
        __hip_atomic_store(master, 0u, __ATOMIC_RELAXED, __HIP_MEMORY_SCOPE_AGENT);
        for (int g = 0; g < 8; ++g)
          __hip_atomic_store(&cnt[g * 16], 0u, __ATOMIC_RELAXED,
                             __HIP_MEMORY_SCOPE_AGENT);
        __hip_atomic_store(magic, BAR_MAGIC, __ATOMIC_RELEASE,
                           __HIP_MEMORY_SCOPE_AGENT);
      }
    } else {
      while (__hip_atomic_load(magic, __ATOMIC_ACQUIRE,
                               __HIP_MEMORY_SCOPE_AGENT) != BAR_MAGIC)
        __builtin_amdgcn_s_sleep(1);
    }
    const uint32_t my = __hip_atomic_load(sense, __ATOMIC_ACQUIRE,
                                          __HIP_MEMORY_SCOPE_AGENT);
    const int g = blockIdx.x >> 6;  // 8 groups of 64 blocks
    const uint32_t old = __hip_atomic_fetch_add(&cnt[g * 16], 1u,
                                                __ATOMIC_ACQ_REL,
                                                __HIP_MEMORY_SCOPE_AGENT);
    if (old == 63u) {
      const uint32_t old2 = __hip_atomic_fetch_add(master, 1u,
                                                   __ATOMIC_ACQ_REL,
                                                   __HIP_MEMORY_SCOPE_AGENT);
      if (old2 == 7u) {
        // last block grid-wide: reset and release
        for (int gg = 0; gg < 8; ++gg)
          __hip_atomic_store(&cnt[gg * 16], 0u, __ATOMIC_RELAXED,
                             __HIP_MEMORY_SCOPE_AGENT);
        __hip_atomic_store(master, 0u, __ATOMIC_RELAXED,
                           __HIP_MEMORY_SCOPE_AGENT);
        __threadfence();
        __hip_atomic_store(sense, my ^ 1u, __ATOMIC_RELEASE,
                           __HIP_MEMORY_SCOPE_AGENT);
      } else {
        while (__hip_atomic_load(sense, __ATOMIC_ACQUIRE,
                                 __HIP_MEMORY_SCOPE_AGENT) == my)
          __builtin_amdgcn_s_sleep(1);
      }
    } else {
      while (__hip_atomic_load(sense, __ATOMIC_ACQUIRE,
                               __HIP_MEMORY_SCOPE_AGENT) == my)
        __builtin_amdgcn_s_sleep(1);
    }
  }
  __syncthreads();
  __threadfence();   // acquire for every thread's subsequent reads
}

// ---------------- Fused single-node kernel: 512 blocks x 512 threads --------
// Phase A (block g: t = g&127, portion p = g>>7): scan all 512 b for t
//   (x4 redundant across portions, fully parallel), p==0 writes vT,
//   presence bitmap in LDS.
// Phase B: portion p emits d in [p*256, p*256+256) for each present row;
//   two rows in flight (256-thread groups) + paired-row ILP.
// grid_barrier
// Phase C (block g == b): transposed-LDS extraction (r6 k_acc body).
__global__ void __launch_bounds__(NTHR, 4) k_all(const float* __restrict__ x,
                                                 const float* __restrict__ w,
                                                 int* __restrict__ vt,
                                                 uint32_t* __restrict__ tab,
                                                 uint32_t* __restrict__ bar,
                                                 float* __restrict__ out,
                                                 TFKeys K) {
  const int g = blockIdx.x;
  const int tid = threadIdx.x;
  const int t = g & 127;
  const int p = g >> 7;

  __shared__ uint32_t s_bm[2];
  __shared__ int s_rows[ICAP];
  __shared__ __align__(16) uint32_t s_tab2[32 * TSTRIDE];  // 16.9 KB
  __shared__ int s_list[BITSZ];
  __shared__ int s_wcnt[2];
  __shared__ int s_anyfb;

  // ---- phase A ----
  if (tid < 2) s_bm[tid] = 0u;
  __syncthreads();
  {
    const int b = tid;
    const int idx = scan_idx(((uint32_t)b << 7) + (uint32_t)t, K.ck0, K.ck1);
    // x_bits linear index: b*(D_IN*BITSZ) + idx*BITSZ + t
    const float ux = runif(K.xk0, K.xk1,
        ((uint32_t)b << 17) + ((uint32_t)idx << 7) + (uint32_t)t);
    const int xb = (ux <= x[b * D_IN + idx]) ? 1 : 0;
    if (p == 0) vt[t * BATCH + b] = xb ? idx : -1;
    if (xb && idx >= IBASE) {
      const int bp = idx - IBASE;
      atomicOr(&s_bm[bp >> 5], 1u << (bp & 31));
    }
  }
  __syncthreads();

  // ---- phase B ----
  {
    const unsigned long long bm = (unsigned long long)s_bm[0] |
                                  ((unsigned long long)s_bm[1] << 32);
    const int cnt = __popcll(bm);
    if (tid < 64 && ((bm >> tid) & 1ull))
      s_rows[__popcll(bm & ((1ull << tid) - 1ull))] = tid;
    __syncthreads();

    const int grp = tid >> 8;            // row-parity group
    const int dl = tid & 255;
    const int d = p * 256 + dl;
    const int wv = (tid >> 6) & 3;
    const int wbase = (p << 3) + (wv << 1);
    const int lane = tid & 63;
    const uint32_t nbase = ((uint32_t)d << 7) + (uint32_t)t;
    for (int r = grp; r < cnt; r += 4) {
      const int j0 = s_rows[r];
      const bool have1 = (r + 2) < cnt;
      const int j1 = have1 ? s_rows[r + 2] : j0;
      const int i0 = IBASE + j0, i1 = IBASE + j1;
      const float w0 = w[i0 * D_OUT + d];     // independent loads first
      const float w1 = w[i1 * D_OUT + d];
      // w_bits linear index: i*(D_OUT*BITSZ) + d*BITSZ + t
      const float u0 = runif(K.wk0, K.wk1, ((uint32_t)i0 << 17) + nbase);
      const float u1 = runif(K.wk0, K.wk1, ((uint32_t)i1 << 17) + nbase);
      const unsigned long long m0 = __ballot(u0 <= w0);
      uint32_t* row0 = tab + (((t << 6) + j0) << 5);
      if (lane == 0)  row0[wbase]     = (uint32_t)m0;
      if (lane == 32) row0[wbase + 1] = (uint32_t)(m0 >> 32);
      if (have1) {
        const unsigned long long m1 = __ballot(u1 <= w1);
        uint32_t* row1 = tab + (((t << 6) + j1) << 5);
        if (lane == 0)  row1[wbase]     = (uint32_t)m1;
        if (lane == 32) row1[wbase + 1] = (uint32_t)(m1 >> 32);
      }
    }
  }

  grid_barrier(bar);

  // ---- phase C: block == b ----
  const int b = g;
  if (tid == 0) s_anyfb = 0;

  unsigned long long mb = 0;
  int code = -1;
  bool act = false;
  if (tid < BITSZ) {
    code = vt[tid * BATCH + b];  // t = tid
    act = code >= 0;
    mb = __ballot(act);
    if ((tid & 63) == 0) s_wcnt[tid >> 6] = __popcll(mb);
  }
  __syncthreads();
  const int m = s_wcnt[0] + s_wcnt[1];
  const int m4 = (m + 3) & ~3;
  if (tid < BITSZ && act) {
    const int lane = tid & 63;
    const int pos = ((tid >= 64) ? s_wcnt[0] : 0) +
                    __popcll(mb & ((1ull << lane) - 1ull));
    s_list[pos] = (code << 7) | tid;  // idx<<7 | t
    if (code < IBASE) atomicOr(&s_anyfb, 1);
  }
  __syncthreads();

  if (s_anyfb == 0) {
    const int wrd = tid & 31;
    for (int jj = tid >> 5; jj < m; jj += 16) {
      const int e = s_list[jj];
      const int i = e >> 7, tt = e & 127;
      s_tab2[wrd * TSTRIDE + jj] = tab[(((tt << 6) + (i - IBASE)) << 5) + wrd];
    }
    if (tid < 32)
      for (int jj = m; jj < m4; ++jj) s_tab2[tid * TSTRIDE + jj] = 0u;
    __syncthreads();

    const int dw0 = tid >> 5, db = tid & 31;
    const uint32_t* c0 = &s_tab2[dw0 * TSTRIDE];
    const uint32_t* c1 = &s_tab2[(dw0 + 16) * TSTRIDE];
    int a0 = 0, a1 = 0;
    for (int k = 0; k < m4; k += 4) {
      const uint4 r0 = *(const uint4*)(c0 + k);  // ds_read_b128, broadcast
      const uint4 r1 = *(const uint4*)(c1 + k);
      a0 += (r0.x >> db) & 1u; a0 += (r0.y >> db) & 1u;
      a0 += (r0.z >> db) & 1u; a0 += (r0.w >> db) & 1u;
      a1 += (r1.x >> db) & 1u; a1 += (r1.y >> db) & 1u;
      a1 += (r1.z >> db) & 1u; a1 += (r1.w >> db) & 1u;
    }
    out[b * D_OUT + tid]       = (float)a0 * (1.0f / (float)BITSZ);
    out[b * D_OUT + tid + 512] = (float)a1 * (1.0f / (float)BITSZ);
  } else {
    // exactness fallback (idx < IBASE): direct ciphers for both d's
    const int d0 = tid, d1 = tid + 512;
    int a0 = 0, a1 = 0;
    for (int jj = 0; jj < m; ++jj) {
      const int e = s_list[jj];
      const int i = e >> 7, tt = e & 127;
      const float u0 = runif(K.wk0, K.wk1,
          ((uint32_t)i << 17) + ((uint32_t)d0 << 7) + (uint32_t)tt);
      const float u1 = runif(K.wk0, K.wk1,
          ((uint32_t)i << 17) + ((uint32_t)d1 << 7) + (uint32_t)tt);
      a0 += (u0 <= w[i * D_OUT + d0]) ? 1 : 0;
      a1 += (u1 <= w[i * D_OUT + d1]) ? 1 : 0;
    }
    out[b * D_OUT + d0] = (float)a0 * (1.0f / (float)BITSZ);
    out[b * D_OUT + d1] = (float)a1 * (1.0f / (float)BITSZ);
  }
}

// ---------------- 3-kernel fallback path (r6, proven; tiny-ws only) ---------
__global__ void __launch_bounds__(256) k_idx(const float* __restrict__ x,
                                             int* __restrict__ v,
                                             uint32_t ck0, uint32_t ck1,
                                             uint32_t xk0, uint32_t xk1) {
  const int tid = blockIdx.x * 256 + threadIdx.x;
  const int b = tid >> 7;
  const int t = tid & 127;
  const int idx = scan_idx((uint32_t)tid, ck0, ck1);
  const float ux = runif(xk0, xk1,
      ((uint32_t)b << 17) + ((uint32_t)idx << 7) + (uint32_t)t);
  const int xb = (ux <= x[b * D_IN + idx]) ? 1 : 0;
  v[tid] = xb ? idx : -1;
}

__global__ void __launch_bounds__(1024) k_acc_fb(const float* __restrict__ w,
                                                 const int* __restrict__ v,
                                                 float* __restrict__ out,
                                                 uint32_t wk0, uint32_t wk1) {
  const int b = blockIdx.x;
  const int tid = threadIdx.x;
  __shared__ int sv[BITSZ];
  if (tid < BITSZ) sv[tid] = v[b * BITSZ + tid];
  __syncthreads();
  int acc = 0;
  for (int t = 0; t < BITSZ; ++t) {
    const int i = sv[t];
    if (i < 0) continue;
    const float u = runif(wk0, wk1,
        ((uint32_t)i << 17) + ((uint32_t)tid << 7) + (uint32_t)t);
    acc += (u <= w[i * D_OUT + tid]) ? 1 : 0;
  }
  out[b * D_OUT + tid] = (float)acc * (1.0f / (float)BITSZ);
}

static TFKeys derive_keys() {
  TFKeys K;
  // partitionable split: key_i = both output words of E_{(0,42)}(0, i)
  uint32_t a0 = 0, a1 = 0; threefry2x32(0u, 42u, a0, a1); K.xk0 = a0; K.xk1 = a1;
  uint32_t b0 = 0, b1 = 1; threefry2x32(0u, 42u, b0, b1); K.wk0 = b0; K.wk1 = b1;
  uint32_t c0 = 0, c1 = 2; threefry2x32(0u, 42u, c0, c1); K.ck0 = c0; K.ck1 = c1;
  return K;
}

extern "C" void kernel_launch(void* const* d_in, const int* in_sizes, int n_in,
                              void* d_out, int out_size, void* d_ws, size_t ws_size,
                              hipStream_t stream) {
  const float* x = (const float*)d_in[0];
  const float* w = (const float*)d_in[1];
  if (n_in >= 2 && in_sizes[0] == D_IN * D_OUT && in_sizes[1] == BATCH * D_IN) {
    const float* tmp = x; x = w; w = tmp;
  }
  float* out = (float*)d_out;
  char* ws = (char*)d_ws;
  int* v = (int*)(ws + WS_V_OFF);
  int* vt = (int*)(ws + WS_VT_OFF);
  uint32_t* tab = (uint32_t*)(ws + WS_TAB_OFF);
  uint32_t* bar = (uint32_t*)(ws + WS_BAR_OFF);

  const TFKeys K = derive_keys();

  if (ws_size >= WS_NEEDED) {
    hipLaunchKernelGGL(k_all, dim3(NBLK), dim3(NTHR), 0, stream,
                       x, w, vt, tab, bar, out, K);
  } else {
    // tiny-ws fallback: direct-cipher 2-kernel path (bit-identical output)
    hipLaunchKernelGGL(k_idx, dim3((BATCH * BITSZ) / 256), dim3(256), 0, stream,
                       x, v, K.ck0, K.ck1, K.xk0, K.xk1);
    hipLaunchKernelGGL(k_acc_fb, dim3(BATCH), dim3(1024), 0, stream,
                       w, v, out, K.wk0, K.wk1);
  }
}

// Round 9
// 22.817 us; speedup vs baseline: 9.8091x; 8.7548x over previous
//
#include <hip/hip_runtime.h>
#include <stdint.h>

#define BATCH 512
#define D_IN 1024
#define D_OUT 1024
#define BITSZ 128
#define N_STEPS (D_IN - 2)  // 1022

// Table covers idx in [IBASE, 1024). P(any idx < IBASE) ~ 65536 * 2^-64 ~ 4e-15;
// a direct-cipher fallback in k_acc keeps exactness for the impossible case.
#define IBASE 960
#define ICAP 64  // table rows per t column

// ws layout (nothing needs zeroing)
#define WS_V_OFF 0u
#define WS_V_BYTES (BATCH * BITSZ * 4u)            // v[b*128+t]
#define WS_TAB_OFF (WS_V_OFF + WS_V_BYTES)
#define WS_TAB_BYTES (BITSZ * ICAP * 32u * 4u)     // 1 MB
#define WS_NEEDED (WS_TAB_OFF + WS_TAB_BYTES)

// k_acc transposed staging: 32 d-word columns, padded stride (132*4B = 528B:
// 16B-aligned columns; bank(jj,wrd) = (4*wrd+jj)%32 -> spread on writes).
#define TSTRIDE 132

struct TFKeys { uint32_t xk0, xk1, wk0, wk1, ck0, ck1; };

__host__ __device__ __forceinline__ uint32_t rotl32(uint32_t x, uint32_t d) {
  return (x << d) | (x >> (32u - d));
}

// Threefry-2x32, 20 rounds, exactly as jax/_src/prng.py lowering.
__host__ __device__ __forceinline__ void threefry2x32(uint32_t k0, uint32_t k1,
                                                      uint32_t& x0, uint32_t& x1) {
  const uint32_t k2 = k0 ^ k1 ^ 0x1BD11BDAu;
  x0 += k0; x1 += k1;
#define TFR(r) { x0 += x1; x1 = rotl32(x1, (r)); x1 ^= x0; }
  TFR(13) TFR(15) TFR(26) TFR(6)
  x0 += k1; x1 += k2 + 1u;
  TFR(17) TFR(29) TFR(16) TFR(24)
  x0 += k2; x1 += k0 + 2u;
  TFR(13) TFR(15) TFR(26) TFR(6)
  x0 += k0; x1 += k1 + 3u;
  TFR(17) TFR(29) TFR(16) TFR(24)
  x0 += k1; x1 += k2 + 4u;
  TFR(13) TFR(15) TFR(26) TFR(6)
  x0 += k2; x1 += k0 + 5u;
#undef TFR
}

// jax_threefry_partitionable random_bits -> uniform [0,1):
// counts=(0,n), 20-round threefry, 32-bit fold, mantissa trick.
__device__ __forceinline__ float runif(uint32_t k0, uint32_t k1, uint32_t n) {
  uint32_t x0 = 0u, x1 = n;
  threefry2x32(k0, k1, x0, x1);
  const uint32_t b = x0 ^ x1;
  return __uint_as_float((b >> 9) | 0x3f800000u) - 1.0f;
}

// idx = max row s+1 whose coin is False, scanned top-down in speculative
// ILP-4 batches (4 independent ciphers hide the dependent threefry chain).
__device__ __forceinline__ int scan_idx(uint32_t bt, uint32_t ck0, uint32_t ck1) {
  int idx = 0;
  int s;
  for (s = N_STEPS - 1; s >= 3; s -= 4) {
    const float u0 = runif(ck0, ck1, ((uint32_t)(s)     << 16) + bt);
    const float u1 = runif(ck0, ck1, ((uint32_t)(s - 1) << 16) + bt);
    const float u2 = runif(ck0, ck1, ((uint32_t)(s - 2) << 16) + bt);
    const float u3 = runif(ck0, ck1, ((uint32_t)(s - 3) << 16) + bt);
    if (u0 > 0.5f) { idx = s + 1; break; }
    if (u1 > 0.5f) { idx = s;     break; }
    if (u2 > 0.5f) { idx = s - 1; break; }
    if (u3 > 0.5f) { idx = s - 2; break; }
  }
  if (idx == 0 && s < 3) {  // tail: s = 1 and s = 0
    const float u0 = runif(ck0, ck1, (1u << 16) + bt);
    const float u1 = runif(ck0, ck1, bt);
    if (u0 > 0.5f)      idx = 2;
    else if (u1 > 0.5f) idx = 1;
  }
  return idx;
}

// Node 1: block = (t, d-half h). 256 blocks x 512 threads.
// Phase A: one scan per thread (b = tid); h==0 writes v; presence via
//   shfl-OR butterfly + 8 per-wave LDS slots (NO LDS atomics).
// Phase B: emit each present row's 512-bit d-half; rows processed in ILP-2
//   pairs (independent cipher chains), ballot-packed to the global table.
__global__ void __launch_bounds__(512) k_tabx(const float* __restrict__ x,
                                              const float* __restrict__ w,
                                              int* __restrict__ v,
                                              uint32_t* __restrict__ tab,
                                              TFKeys K) {
  const int t = blockIdx.x >> 1;
  const int h = blockIdx.x & 1;
  const int tid = threadIdx.x;

  __shared__ unsigned long long s_bmw[8];
  __shared__ int s_rows[ICAP];

  // ---- phase A ----
  const int b = tid;
  const int idx = scan_idx(((uint32_t)b << 7) + (uint32_t)t, K.ck0, K.ck1);
  // x_bits linear index: b*(D_IN*BITSZ) + idx*BITSZ + t
  const float ux = runif(K.xk0, K.xk1,
      ((uint32_t)b << 17) + ((uint32_t)idx << 7) + (uint32_t)t);
  const int xb = (ux <= x[b * D_IN + idx]) ? 1 : 0;
  if (h == 0) v[b * BITSZ + t] = xb ? idx : -1;

  unsigned long long me =
      (xb && idx >= IBASE) ? (1ull << (idx - IBASE)) : 0ull;
#pragma unroll
  for (int off = 1; off < 64; off <<= 1) me |= __shfl_xor(me, off);
  if ((tid & 63) == 0) s_bmw[tid >> 6] = me;
  __syncthreads();

  unsigned long long bm = s_bmw[0];
#pragma unroll
  for (int wv = 1; wv < 8; ++wv) bm |= s_bmw[wv];
  const int cnt = __popcll(bm);
  if (tid < 64 && ((bm >> tid) & 1ull))
    s_rows[__popcll(bm & ((1ull << tid) - 1ull))] = tid;
  __syncthreads();

  // ---- phase B ----
  const int d = h * 512 + tid;
  const int lane = tid & 63;
  const int wbase = (d >> 5) & ~1;  // even word pair for this wave
  const uint32_t nbase = ((uint32_t)d << 7) + (uint32_t)t;
  const float* wcol = w + d;
  for (int r = 0; r < cnt; r += 2) {
    const int j0 = s_rows[r];
    const bool have1 = (r + 1) < cnt;
    const int j1 = have1 ? s_rows[r + 1] : j0;
    const int i0 = IBASE + j0, i1 = IBASE + j1;
    const float w0 = wcol[i0 * D_OUT];  // independent loads first
    const float w1 = wcol[i1 * D_OUT];
    // w_bits linear index: i*(D_OUT*BITSZ) + d*BITSZ + t
    const float u0 = runif(K.wk0, K.wk1, ((uint32_t)i0 << 17) + nbase);
    const float u1 = runif(K.wk0, K.wk1, ((uint32_t)i1 << 17) + nbase);
    const unsigned long long m0 = __ballot(u0 <= w0);
    uint32_t* row0 = tab + (((t << 6) + j0) << 5);
    if (lane == 0)  row0[wbase]     = (uint32_t)m0;
    if (lane == 32) row0[wbase + 1] = (uint32_t)(m0 >> 32);
    if (have1) {
      const unsigned long long m1 = __ballot(u1 <= w1);
      uint32_t* row1 = tab + (((t << 6) + j1) << 5);
      if (lane == 0)  row1[wbase]     = (uint32_t)m1;
      if (lane == 32) row1[wbase + 1] = (uint32_t)(m1 >> 32);
    }
  }
}

// Node 2: block per b, 512 threads. Compact active (t,idx), stage rows
// TRANSPOSED into LDS ([32 dw][TSTRIDE]), accumulate via ds_read_b128
// (broadcast within half-wave). No LDS atomics (per-wave ballot flags).
__global__ void __launch_bounds__(512) k_acc(const float* __restrict__ w,
                                             const int* __restrict__ v,
                                             const uint32_t* __restrict__ tab,
                                             float* __restrict__ out,
                                             uint32_t wk0, uint32_t wk1,
                                             int use_tab) {
  const int b = blockIdx.x;
  const int tid = threadIdx.x;

  __shared__ __align__(16) uint32_t s_tab2[32 * TSTRIDE];  // 16.9 KB
  __shared__ int s_list[BITSZ];
  __shared__ int s_wcnt[2];
  __shared__ uint32_t s_fb[2];

  unsigned long long mb = 0;
  int code = -1;
  bool act = false;
  if (tid < BITSZ) {
    code = v[b * BITSZ + tid];
    act = code >= 0;
    mb = __ballot(act);
    const unsigned long long fbm = __ballot(act && code < IBASE);
    if ((tid & 63) == 0) {
      s_wcnt[tid >> 6] = __popcll(mb);
      s_fb[tid >> 6] = (fbm != 0ull) ? 1u : 0u;
    }
  }
  __syncthreads();
  const int m = s_wcnt[0] + s_wcnt[1];
  const int m4 = (m + 3) & ~3;
  const bool anyfb = (!use_tab) || (s_fb[0] | s_fb[1]);
  if (tid < BITSZ && act) {
    const int lane = tid & 63;
    const int pos = ((tid >= 64) ? s_wcnt[0] : 0) +
                    __popcll(mb & ((1ull << lane) - 1ull));
    s_list[pos] = (code << 7) | tid;  // idx<<7 | t
  }
  __syncthreads();

  if (!anyfb) {
    // Transposed staging: column = d-word (wrd), row index jj along stride.
    const int wrd = tid & 31;
    for (int jj = tid >> 5; jj < m; jj += 16) {
      const int e = s_list[jj];
      const int i = e >> 7, t = e & 127;
      s_tab2[wrd * TSTRIDE + jj] = tab[(((t << 6) + (i - IBASE)) << 5) + wrd];
    }
    if (tid < 32)
      for (int jj = m; jj < m4; ++jj) s_tab2[tid * TSTRIDE + jj] = 0u;
    __syncthreads();

    const int dw0 = tid >> 5, db = tid & 31;  // dw0 in 0..15
    const uint32_t* c0 = &s_tab2[dw0 * TSTRIDE];
    const uint32_t* c1 = &s_tab2[(dw0 + 16) * TSTRIDE];
    int a0 = 0, a1 = 0;
    for (int k = 0; k < m4; k += 4) {
      const uint4 r0 = *(const uint4*)(c0 + k);  // ds_read_b128, broadcast
      const uint4 r1 = *(const uint4*)(c1 + k);
      a0 += (r0.x >> db) & 1u; a0 += (r0.y >> db) & 1u;
      a0 += (r0.z >> db) & 1u; a0 += (r0.w >> db) & 1u;
      a1 += (r1.x >> db) & 1u; a1 += (r1.y >> db) & 1u;
      a1 += (r1.z >> db) & 1u; a1 += (r1.w >> db) & 1u;
    }
    out[b * D_OUT + tid]       = (float)a0 * (1.0f / (float)BITSZ);
    out[b * D_OUT + tid + 512] = (float)a1 * (1.0f / (float)BITSZ);
  } else {
    // Correctness fallback (idx < IBASE or tiny ws): direct ciphers, 2 d's.
    const int d0 = tid, d1 = tid + 512;
    int a0 = 0, a1 = 0;
    for (int jj = 0; jj < m; ++jj) {
      const int e = s_list[jj];
      const int i = e >> 7, t = e & 127;
      const float u0 = runif(wk0, wk1,
          ((uint32_t)i << 17) + ((uint32_t)d0 << 7) + (uint32_t)t);
      const float u1 = runif(wk0, wk1,
          ((uint32_t)i << 17) + ((uint32_t)d1 << 7) + (uint32_t)t);
      a0 += (u0 <= w[i * D_OUT + d0]) ? 1 : 0;
      a1 += (u1 <= w[i * D_OUT + d1]) ? 1 : 0;
    }
    out[b * D_OUT + d0] = (float)a0 * (1.0f / (float)BITSZ);
    out[b * D_OUT + d1] = (float)a1 * (1.0f / (float)BITSZ);
  }
}

// Tiny-ws fallback: standalone scan kernel (k_acc then runs direct-cipher).
__global__ void __launch_bounds__(256) k_idx(const float* __restrict__ x,
                                             int* __restrict__ v,
                                             uint32_t ck0, uint32_t ck1,
                                             uint32_t xk0, uint32_t xk1) {
  const int tid = blockIdx.x * 256 + threadIdx.x;
  const int b = tid >> 7;
  const int t = tid & 127;
  const int idx = scan_idx((uint32_t)tid, ck0, ck1);
  const float ux = runif(xk0, xk1,
      ((uint32_t)b << 17) + ((uint32_t)idx << 7) + (uint32_t)t);
  const int xb = (ux <= x[b * D_IN + idx]) ? 1 : 0;
  v[tid] = xb ? idx : -1;
}

static TFKeys derive_keys() {
  TFKeys K;
  // partitionable split: key_i = both output words of E_{(0,42)}(0, i)
  uint32_t a0 = 0, a1 = 0; threefry2x32(0u, 42u, a0, a1); K.xk0 = a0; K.xk1 = a1;
  uint32_t b0 = 0, b1 = 1; threefry2x32(0u, 42u, b0, b1); K.wk0 = b0; K.wk1 = b1;
  uint32_t c0 = 0, c1 = 2; threefry2x32(0u, 42u, c0, c1); K.ck0 = c0; K.ck1 = c1;
  return K;
}

extern "C" void kernel_launch(void* const* d_in, const int* in_sizes, int n_in,
                              void* d_out, int out_size, void* d_ws, size_t ws_size,
                              hipStream_t stream) {
  const float* x = (const float*)d_in[0];
  const float* w = (const float*)d_in[1];
  if (n_in >= 2 && in_sizes[0] == D_IN * D_OUT && in_sizes[1] == BATCH * D_IN) {
    const float* tmp = x; x = w; w = tmp;
  }
  float* out = (float*)d_out;
  char* ws = (char*)d_ws;
  int* v = (int*)(ws + WS_V_OFF);
  uint32_t* tab = (uint32_t*)(ws + WS_TAB_OFF);

  const int use_tab = (ws_size >= WS_NEEDED) ? 1 : 0;
  const TFKeys K = derive_keys();

  if (use_tab) {
    hipLaunchKernelGGL(k_tabx, dim3(BITSZ * 2), dim3(512), 0, stream,
                       x, w, v, tab, K);
  } else {
    hipLaunchKernelGGL(k_idx, dim3((BATCH * BITSZ) / 256), dim3(256), 0, stream,
                       x, v, K.ck0, K.ck1, K.xk0, K.xk1);
  }
  hipLaunchKernelGGL(k_acc, dim3(BATCH), dim3(512), 0, stream,
                     w, v, tab, out, K.wk0, K.wk1, use_tab);
}

// Round 10
// 22.291 us; speedup vs baseline: 10.0405x; 1.0236x over previous
//
#include <hip/hip_runtime.h>
#include <stdint.h>

#define BATCH 512
#define D_IN 1024
#define D_OUT 1024
#define BITSZ 128
#define N_STEPS (D_IN - 2)  // 1022

// Table covers idx in [IBASE, 1024). P(any idx < IBASE) ~ 65536 * 2^-64 ~ 4e-15;
// a direct-cipher fallback in k_acc keeps exactness for the impossible case.
#define IBASE 960
#define ICAP 64  // table rows per t column

// ws layout (nothing needs zeroing)
#define WS_V_OFF 0u
#define WS_V_BYTES (BATCH * BITSZ * 4u)            // v[b*128+t]
#define WS_TAB_OFF (WS_V_OFF + WS_V_BYTES)
#define WS_TAB_BYTES (BITSZ * ICAP * 32u * 4u)     // 1 MB
#define WS_NEEDED (WS_TAB_OFF + WS_TAB_BYTES)

// k_acc transposed staging: 32 d-word columns, padded stride (132*4B = 528B:
// 16B-aligned columns; adjacent columns 4 banks apart -> conflict-free).
#define TSTRIDE 132

struct TFKeys { uint32_t xk0, xk1, wk0, wk1, ck0, ck1; };

__host__ __device__ __forceinline__ uint32_t rotl32(uint32_t x, uint32_t d) {
  return (x << d) | (x >> (32u - d));
}

// Threefry-2x32, 20 rounds, exactly as jax/_src/prng.py lowering.
__host__ __device__ __forceinline__ void threefry2x32(uint32_t k0, uint32_t k1,
                                                      uint32_t& x0, uint32_t& x1) {
  const uint32_t k2 = k0 ^ k1 ^ 0x1BD11BDAu;
  x0 += k0; x1 += k1;
#define TFR(r) { x0 += x1; x1 = rotl32(x1, (r)); x1 ^= x0; }
  TFR(13) TFR(15) TFR(26) TFR(6)
  x0 += k1; x1 += k2 + 1u;
  TFR(17) TFR(29) TFR(16) TFR(24)
  x0 += k2; x1 += k0 + 2u;
  TFR(13) TFR(15) TFR(26) TFR(6)
  x0 += k0; x1 += k1 + 3u;
  TFR(17) TFR(29) TFR(16) TFR(24)
  x0 += k1; x1 += k2 + 4u;
  TFR(13) TFR(15) TFR(26) TFR(6)
  x0 += k2; x1 += k0 + 5u;
#undef TFR
}

// jax_threefry_partitionable random_bits -> uniform [0,1):
// counts=(0,n), 20-round threefry, 32-bit fold, mantissa trick.
__device__ __forceinline__ float runif(uint32_t k0, uint32_t k1, uint32_t n) {
  uint32_t x0 = 0u, x1 = n;
  threefry2x32(k0, k1, x0, x1);
  const uint32_t b = x0 ^ x1;
  return __uint_as_float((b >> 9) | 0x3f800000u) - 1.0f;
}

// idx = max row s+1 whose coin is False, scanned top-down in speculative
// ILP-4 batches (4 independent ciphers hide the dependent threefry chain).
__device__ __forceinline__ int scan_idx(uint32_t bt, uint32_t ck0, uint32_t ck1) {
  int idx = 0;
  int s;
  for (s = N_STEPS - 1; s >= 3; s -= 4) {
    const float u0 = runif(ck0, ck1, ((uint32_t)(s)     << 16) + bt);
    const float u1 = runif(ck0, ck1, ((uint32_t)(s - 1) << 16) + bt);
    const float u2 = runif(ck0, ck1, ((uint32_t)(s - 2) << 16) + bt);
    const float u3 = runif(ck0, ck1, ((uint32_t)(s - 3) << 16) + bt);
    if (u0 > 0.5f) { idx = s + 1; break; }
    if (u1 > 0.5f) { idx = s;     break; }
    if (u2 > 0.5f) { idx = s - 1; break; }
    if (u3 > 0.5f) { idx = s - 2; break; }
  }
  if (idx == 0 && s < 3) {  // tail: s = 1 and s = 0
    const float u0 = runif(ck0, ck1, (1u << 16) + bt);
    const float u1 = runif(ck0, ck1, bt);
    if (u0 > 0.5f)      idx = 2;
    else if (u1 > 0.5f) idx = 1;
  }
  return idx;
}

// Node 1: block = (t, d-half h). 256 blocks x 512 threads.
// Phase A: one scan per thread (b = tid); h==0 writes v; presence via
//   shfl-OR butterfly + 8 per-wave LDS slots (no LDS atomics).
// Phase B: emit each present row's 512-bit d-half; FOUR rows in flight
//   (independent cipher chains + independent w loads), ballot-packed.
__global__ void __launch_bounds__(512) k_tabx(const float* __restrict__ x,
                                              const float* __restrict__ w,
                                              int* __restrict__ v,
                                              uint32_t* __restrict__ tab,
                                              TFKeys K) {
  const int t = blockIdx.x >> 1;
  const int h = blockIdx.x & 1;
  const int tid = threadIdx.x;

  __shared__ unsigned long long s_bmw[8];
  __shared__ int s_rows[ICAP];

  // ---- phase A ----
  const int b = tid;
  const int idx = scan_idx(((uint32_t)b << 7) + (uint32_t)t, K.ck0, K.ck1);
  // x_bits linear index: b*(D_IN*BITSZ) + idx*BITSZ + t
  const float ux = runif(K.xk0, K.xk1,
      ((uint32_t)b << 17) + ((uint32_t)idx << 7) + (uint32_t)t);
  const int xb = (ux <= x[b * D_IN + idx]) ? 1 : 0;
  if (h == 0) v[b * BITSZ + t] = xb ? idx : -1;

  unsigned long long me =
      (xb && idx >= IBASE) ? (1ull << (idx - IBASE)) : 0ull;
#pragma unroll
  for (int off = 1; off < 64; off <<= 1) me |= __shfl_xor(me, off);
  if ((tid & 63) == 0) s_bmw[tid >> 6] = me;
  __syncthreads();

  unsigned long long bm = s_bmw[0];
#pragma unroll
  for (int wv = 1; wv < 8; ++wv) bm |= s_bmw[wv];
  const int cnt = __popcll(bm);
  if (tid < 64 && ((bm >> tid) & 1ull))
    s_rows[__popcll(bm & ((1ull << tid) - 1ull))] = tid;
  __syncthreads();

  // ---- phase B: 4 rows in flight ----
  const int d = h * 512 + tid;
  const int lane = tid & 63;
  const int wbase = (d >> 5) & ~1;  // even word pair for this wave
  const uint32_t nbase = ((uint32_t)d << 7) + (uint32_t)t;
  const float* wcol = w + d;
  for (int r = 0; r < cnt; r += 4) {
    const bool h1 = (r + 1) < cnt, h2 = (r + 2) < cnt, h3 = (r + 3) < cnt;
    const int j0 = s_rows[r];
    const int j1 = h1 ? s_rows[r + 1] : j0;
    const int j2 = h2 ? s_rows[r + 2] : j0;
    const int j3 = h3 ? s_rows[r + 3] : j0;
    const int i0 = IBASE + j0, i1 = IBASE + j1;
    const int i2 = IBASE + j2, i3 = IBASE + j3;
    const float w0 = wcol[i0 * D_OUT];  // 4 independent loads first
    const float w1 = wcol[i1 * D_OUT];
    const float w2 = wcol[i2 * D_OUT];
    const float w3 = wcol[i3 * D_OUT];
    // w_bits linear index: i*(D_OUT*BITSZ) + d*BITSZ + t
    const float u0 = runif(K.wk0, K.wk1, ((uint32_t)i0 << 17) + nbase);
    const float u1 = runif(K.wk0, K.wk1, ((uint32_t)i1 << 17) + nbase);
    const float u2 = runif(K.wk0, K.wk1, ((uint32_t)i2 << 17) + nbase);
    const float u3 = runif(K.wk0, K.wk1, ((uint32_t)i3 << 17) + nbase);
    {
      const unsigned long long m0 = __ballot(u0 <= w0);
      uint32_t* row0 = tab + (((t << 6) + j0) << 5);
      if (lane == 0)  row0[wbase]     = (uint32_t)m0;
      if (lane == 32) row0[wbase + 1] = (uint32_t)(m0 >> 32);
    }
    if (h1) {
      const unsigned long long m1 = __ballot(u1 <= w1);
      uint32_t* row1 = tab + (((t << 6) + j1) << 5);
      if (lane == 0)  row1[wbase]     = (uint32_t)m1;
      if (lane == 32) row1[wbase + 1] = (uint32_t)(m1 >> 32);
    }
    if (h2) {
      const unsigned long long m2 = __ballot(u2 <= w2);
      uint32_t* row2 = tab + (((t << 6) + j2) << 5);
      if (lane == 0)  row2[wbase]     = (uint32_t)m2;
      if (lane == 32) row2[wbase + 1] = (uint32_t)(m2 >> 32);
    }
    if (h3) {
      const unsigned long long m3 = __ballot(u3 <= w3);
      uint32_t* row3 = tab + (((t << 6) + j3) << 5);
      if (lane == 0)  row3[wbase]     = (uint32_t)m3;
      if (lane == 32) row3[wbase + 1] = (uint32_t)(m3 >> 32);
    }
  }
}

// Node 2: block per b, 1024 threads (one d each; 2 blocks/CU = 32 waves/CU).
// Compact active (t,idx), stage rows TRANSPOSED into LDS ([32 dw][TSTRIDE]),
// extract via 16 ds_read_b128 per thread (broadcast, conflict-free).
__global__ void __launch_bounds__(1024) k_acc(const float* __restrict__ w,
                                              const int* __restrict__ v,
                                              const uint32_t* __restrict__ tab,
                                              float* __restrict__ out,
                                              uint32_t wk0, uint32_t wk1,
                                              int use_tab) {
  const int b = blockIdx.x;
  const int tid = threadIdx.x;  // == d

  __shared__ __align__(16) uint32_t s_tab2[32 * TSTRIDE];  // 16.9 KB
  __shared__ int s_list[BITSZ];
  __shared__ int s_wcnt[2];
  __shared__ uint32_t s_fb[2];

  unsigned long long mb = 0;
  int code = -1;
  bool act = false;
  if (tid < BITSZ) {
    code = v[b * BITSZ + tid];
    act = code >= 0;
    mb = __ballot(act);
    const unsigned long long fbm = __ballot(act && code < IBASE);
    if ((tid & 63) == 0) {
      s_wcnt[tid >> 6] = __popcll(mb);
      s_fb[tid >> 6] = (fbm != 0ull) ? 1u : 0u;
    }
  }
  __syncthreads();
  const int m = s_wcnt[0] + s_wcnt[1];
  const int m4 = (m + 3) & ~3;
  const bool anyfb = (!use_tab) || (s_fb[0] | s_fb[1]);
  if (tid < BITSZ && act) {
    const int lane = tid & 63;
    const int pos = ((tid >= 64) ? s_wcnt[0] : 0) +
                    __popcll(mb & ((1ull << lane) - 1ull));
    s_list[pos] = (code << 7) | tid;  // idx<<7 | t
  }
  __syncthreads();

  if (!anyfb) {
    // Transposed staging: thread (jj0 = tid>>5, wrd = tid&31); <=4 rounds.
    const int wrd = tid & 31;
    for (int jj = tid >> 5; jj < m4; jj += 32) {
      uint32_t val = 0u;
      if (jj < m) {
        const int e = s_list[jj];
        const int i = e >> 7, t = e & 127;
        val = tab[(((t << 6) + (i - IBASE)) << 5) + wrd];
      }
      s_tab2[wrd * TSTRIDE + jj] = val;
    }
    __syncthreads();

    const int dw = tid >> 5, db = tid & 31;
    const uint32_t* colp = &s_tab2[dw * TSTRIDE];
    int acc = 0;
    for (int k = 0; k < m4; k += 4) {
      const uint4 r = *(const uint4*)(colp + k);  // ds_read_b128, broadcast
      acc += (r.x >> db) & 1u;
      acc += (r.y >> db) & 1u;
      acc += (r.z >> db) & 1u;
      acc += (r.w >> db) & 1u;
    }
    out[b * D_OUT + tid] = (float)acc * (1.0f / (float)BITSZ);
  } else {
    // Correctness fallback (idx < IBASE or tiny ws): direct ciphers.
    int acc = 0;
    for (int jj = 0; jj < m; ++jj) {
      const int e = s_list[jj];
      const int i = e >> 7, t = e & 127;
      const float u = runif(wk0, wk1,
          ((uint32_t)i << 17) + ((uint32_t)tid << 7) + (uint32_t)t);
      acc += (u <= w[i * D_OUT + tid]) ? 1 : 0;
    }
    out[b * D_OUT + tid] = (float)acc * (1.0f / (float)BITSZ);
  }
}

// Tiny-ws fallback: standalone scan kernel (k_acc then runs direct-cipher).
__global__ void __launch_bounds__(256) k_idx(const float* __restrict__ x,
                                             int* __restrict__ v,
                                             uint32_t ck0, uint32_t ck1,
                                             uint32_t xk0, uint32_t xk1) {
  const int tid = blockIdx.x * 256 + threadIdx.x;
  const int b = tid >> 7;
  const int t = tid & 127;
  const int idx = scan_idx((uint32_t)tid, ck0, ck1);
  const float ux = runif(xk0, xk1,
      ((uint32_t)b << 17) + ((uint32_t)idx << 7) + (uint32_t)t);
  const int xb = (ux <= x[b * D_IN + idx]) ? 1 : 0;
  v[tid] = xb ? idx : -1;
}

static TFKeys derive_keys() {
  TFKeys K;
  // partitionable split: key_i = both output words of E_{(0,42)}(0, i)
  uint32_t a0 = 0, a1 = 0; threefry2x32(0u, 42u, a0, a1); K.xk0 = a0; K.xk1 = a1;
  uint32_t b0 = 0, b1 = 1; threefry2x32(0u, 42u, b0, b1); K.wk0 = b0; K.wk1 = b1;
  uint32_t c0 = 0, c1 = 2; threefry2x32(0u, 42u, c0, c1); K.ck0 = c0; K.ck1 = c1;
  return K;
}

extern "C" void kernel_launch(void* const* d_in, const int* in_sizes, int n_in,
                              void* d_out, int out_size, void* d_ws, size_t ws_size,
                              hipStream_t stream) {
  const float* x = (const float*)d_in[0];
  const float* w = (const float*)d_in[1];
  if (n_in >= 2 && in_sizes[0] == D_IN * D_OUT && in_sizes[1] == BATCH * D_IN) {
    const float* tmp = x; x = w; w = tmp;
  }
  float* out = (float*)d_out;
  char* ws = (char*)d_ws;
  int* v = (int*)(ws + WS_V_OFF);
  uint32_t* tab = (uint32_t*)(ws + WS_TAB_OFF);

  const int use_tab = (ws_size >= WS_NEEDED) ? 1 : 0;
  const TFKeys K = derive_keys();

  if (use_tab) {
    hipLaunchKernelGGL(k_tabx, dim3(BITSZ * 2), dim3(512), 0, stream,
                       x, w, v, tab, K);
  } else {
    hipLaunchKernelGGL(k_idx, dim3((BATCH * BITSZ) / 256), dim3(256), 0, stream,
                       x, v, K.ck0, K.ck1, K.xk0, K.xk1);
  }
  hipLaunchKernelGGL(k_acc, dim3(BATCH), dim3(1024), 0, stream,
                     w, v, tab, out, K.wk0, K.wk1, use_tab);
}